// Round 6
// baseline (364.749 us; speedup 1.0000x reference)
//
#include <hip/hip_runtime.h>

#define N_NODES 50000
#define N_EDGES 600000
#define XS_STRIDE 132            // LDS row stride: 128 + 4 pad
#define PANEL ((size_t)N_NODES * 16)   // floats per 16-col feature panel

// ---------------- graph build ----------------

__global__ void count_edges(const int* __restrict__ dst, int* __restrict__ cnt) {
    int e = blockIdx.x * blockDim.x + threadIdx.x;
    if (e < N_EDGES) atomicAdd(&cnt[dst[e]], 1);
}

// Reserve CSR slots: start[v] = atomicAdd(total, cnt[v]). Row order in col/colw
// is nondeterministic but the edge SET per row is exact; fp32 sum-order jitter
// ~1e-6 << 2e-3 threshold.
__global__ void reserve_rows(const int* __restrict__ cnt, int* __restrict__ start,
                             int* __restrict__ total, float* __restrict__ dinv) {
    int i = blockIdx.x * blockDim.x + threadIdx.x;
    if (i < N_NODES) {
        int c = cnt[i];
        start[i] = atomicAdd(total, c);
        dinv[i] = 1.0f / sqrtf((float)(c + 1));   // +1 self-loop
    }
}

__global__ void csr_fill(const int* __restrict__ srcArr, const int* __restrict__ dstArr,
                         const int* __restrict__ start, int* __restrict__ fill,
                         int* __restrict__ col, float* __restrict__ colw,
                         const float* __restrict__ dinv) {
    int e = blockIdx.x * blockDim.x + threadIdx.x;
    if (e < N_EDGES) {
        int d = dstArr[e];
        int s = srcArr[e];
        int pos = start[d] + atomicAdd(&fill[d], 1);
        col[pos] = s;
        colw[pos] = dinv[s];   // pre-multiplied dinv[src]
    }
}

// ---------------- dense GEMM [N,128]@[128,128] -> panel output ----------------
// block = 256 threads, tile = 64 rows x 128 cols, micro-tile 4x8.
// PIN: input in panel layout (agg output); else row-major (original x).
// Output always panel layout.

template <bool PIN>
__global__ __launch_bounds__(256) void gemm128_t(const float* __restrict__ X,
                                                 const float* __restrict__ W,
                                                 float* __restrict__ T) {
    __shared__ float xs[64 * XS_STRIDE];
    int tid = threadIdx.x;
    int row0 = blockIdx.x * 64;

    #pragma unroll
    for (int i = 0; i < 8; ++i) {
        int fi = tid + i * 256;
        int r  = fi >> 5;
        int c4 = (fi & 31) << 2;
        float4 v = make_float4(0.f, 0.f, 0.f, 0.f);
        int rg = row0 + r;
        if (rg < N_NODES) {
            if (PIN) {
                int f = c4 >> 4, off = c4 & 15;
                v = *(const float4*)&X[(size_t)f * PANEL + (size_t)rg * 16 + off];
            } else {
                v = *(const float4*)&X[(size_t)rg * 128 + c4];
            }
        }
        float* p = &xs[r * XS_STRIDE + c4];
        p[0] = v.x; p[1] = v.y; p[2] = v.z; p[3] = v.w;
    }
    __syncthreads();

    int cg = tid & 15, rg = tid >> 4;
    int c0 = cg * 8, r0 = rg * 4;
    float acc[4][8];
    #pragma unroll
    for (int i = 0; i < 4; ++i)
        #pragma unroll
        for (int j = 0; j < 8; ++j) acc[i][j] = 0.f;

    for (int k0 = 0; k0 < 128; k0 += 4) {
        float4 a[4];
        #pragma unroll
        for (int i = 0; i < 4; ++i) a[i] = *(const float4*)&xs[(r0 + i) * XS_STRIDE + k0];
        #pragma unroll
        for (int kk = 0; kk < 4; ++kk) {
            float4 blo = *(const float4*)&W[(k0 + kk) * 128 + c0];
            float4 bhi = *(const float4*)&W[(k0 + kk) * 128 + c0 + 4];
            #pragma unroll
            for (int i = 0; i < 4; ++i) {
                float av = (kk == 0) ? a[i].x : (kk == 1) ? a[i].y : (kk == 2) ? a[i].z : a[i].w;
                acc[i][0] = fmaf(av, blo.x, acc[i][0]);
                acc[i][1] = fmaf(av, blo.y, acc[i][1]);
                acc[i][2] = fmaf(av, blo.z, acc[i][2]);
                acc[i][3] = fmaf(av, blo.w, acc[i][3]);
                acc[i][4] = fmaf(av, bhi.x, acc[i][4]);
                acc[i][5] = fmaf(av, bhi.y, acc[i][5]);
                acc[i][6] = fmaf(av, bhi.z, acc[i][6]);
                acc[i][7] = fmaf(av, bhi.w, acc[i][7]);
            }
        }
    }

    // write to panel layout: cols c0..c0+7 live in panel c0>>4 at offset c0&15 (0 or 8)
    int f = c0 >> 4, off = c0 & 15;
    #pragma unroll
    for (int i = 0; i < 4; ++i) {
        int r = row0 + r0 + i;
        if (r < N_NODES) {
            float* base = &T[(size_t)f * PANEL + (size_t)r * 16 + off];
            *(float4*)&base[0] = make_float4(acc[i][0], acc[i][1], acc[i][2], acc[i][3]);
            *(float4*)&base[4] = make_float4(acc[i][4], acc[i][5], acc[i][6], acc[i][7]);
        }
    }
}

// ---------------- aggregation over panels ----------------
// outp[f][v][:] = relu(dinv[v]*(sum_e colw[e]*T[f][col[e]] + dinv[v]*T[f][v]) + b[f*16:])
// blockIdx % 8 = feature panel f (-> XCD f via round-robin dispatch; panel = 3.2MB,
// fits the XCD's 4MB L2 so the random gather becomes L2-resident).
// block = 256 threads = 64 nodes x 4 lanes, float4 per lane.

__global__ __launch_bounds__(256) void gcn_aggregate_pn(
        const float* __restrict__ T, const int* __restrict__ start,
        const int* __restrict__ cnt, const int* __restrict__ col,
        const float* __restrict__ colw, const float* __restrict__ dinv,
        const float* __restrict__ bias, float* __restrict__ outp) {
    int f  = blockIdx.x & 7;
    int nb = blockIdx.x >> 3;
    int tid = threadIdx.x;
    int v = nb * 64 + (tid >> 2);
    if (v >= N_NODES) return;
    int j4 = (tid & 3) << 2;

    const float* __restrict__ Tp = T + (size_t)f * PANEL;
    float dv = dinv[v];
    const float4 tv = *(const float4*)&Tp[(size_t)v * 16 + j4];
    float4 acc = make_float4(dv * tv.x, dv * tv.y, dv * tv.z, dv * tv.w);

    int beg = start[v], end = beg + cnt[v];
    int e = beg;
    for (; e + 4 <= end; e += 4) {
        int   s0 = col[e],     s1 = col[e + 1],  s2 = col[e + 2],  s3 = col[e + 3];
        float w0 = colw[e],    w1 = colw[e + 1], w2 = colw[e + 2], w3 = colw[e + 3];
        const float4 t0 = *(const float4*)&Tp[(size_t)s0 * 16 + j4];
        const float4 t1 = *(const float4*)&Tp[(size_t)s1 * 16 + j4];
        const float4 t2 = *(const float4*)&Tp[(size_t)s2 * 16 + j4];
        const float4 t3 = *(const float4*)&Tp[(size_t)s3 * 16 + j4];
        acc.x = fmaf(w0, t0.x, fmaf(w1, t1.x, fmaf(w2, t2.x, fmaf(w3, t3.x, acc.x))));
        acc.y = fmaf(w0, t0.y, fmaf(w1, t1.y, fmaf(w2, t2.y, fmaf(w3, t3.y, acc.y))));
        acc.z = fmaf(w0, t0.z, fmaf(w1, t1.z, fmaf(w2, t2.z, fmaf(w3, t3.z, acc.z))));
        acc.w = fmaf(w0, t0.w, fmaf(w1, t1.w, fmaf(w2, t2.w, fmaf(w3, t3.w, acc.w))));
    }
    for (; e < end; ++e) {
        int s0 = col[e];
        float w0 = colw[e];
        const float4 t0 = *(const float4*)&Tp[(size_t)s0 * 16 + j4];
        acc.x = fmaf(w0, t0.x, acc.x);
        acc.y = fmaf(w0, t0.y, acc.y);
        acc.z = fmaf(w0, t0.z, acc.z);
        acc.w = fmaf(w0, t0.w, acc.w);
    }

    const float4 b4 = *(const float4*)&bias[f * 16 + j4];
    float4 r;
    r.x = fmaxf(fmaf(dv, acc.x, b4.x), 0.f);
    r.y = fmaxf(fmaf(dv, acc.y, b4.y), 0.f);
    r.z = fmaxf(fmaf(dv, acc.z, b4.z), 0.f);
    r.w = fmaxf(fmaf(dv, acc.w, b4.w), 0.f);
    *(float4*)&outp[(size_t)f * PANEL + (size_t)v * 16 + j4] = r;
}

// ---------------- final linear [N,128]@[128,32] + bias, panel input ----------------
// block = 256 = 8 nodes x 32 lanes; h3 row staged via LDS, lane = output column.

__global__ __launch_bounds__(256) void gemm_final_pn(
        const float* __restrict__ Hp, const float* __restrict__ Wl,
        const float* __restrict__ bl, float* __restrict__ out32) {
    __shared__ float sh[8 * 128];
    int tid = threadIdx.x;
    int g = tid >> 5, lane = tid & 31;
    int v = blockIdx.x * 8 + g;          // grid = 6250 exactly
    int c4 = lane << 2;
    int f = c4 >> 4, off = c4 & 15;
    const float4 hv = *(const float4*)&Hp[(size_t)f * PANEL + (size_t)v * 16 + off];
    *(float4*)&sh[g * 128 + c4] = hv;
    __syncthreads();

    float o = bl[lane];
    const float* hrow = &sh[g * 128];
    #pragma unroll 8
    for (int j = 0; j < 128; ++j)
        o = fmaf(hrow[j], Wl[j * 32 + lane], o);
    out32[(size_t)v * 32 + lane] = o;
}

// ---------------- launch ----------------

extern "C" void kernel_launch(void* const* d_in, const int* in_sizes, int n_in,
                              void* d_out, int out_size, void* d_ws, size_t ws_size,
                              hipStream_t stream) {
    const float* x      = (const float*)d_in[0];
    const int*   ei     = (const int*)d_in[1];
    const int*   srcArr = ei;
    const int*   dstArr = ei + N_EDGES;
    const float* W1 = (const float*)d_in[2];
    const float* b1 = (const float*)d_in[3];
    const float* W2 = (const float*)d_in[4];
    const float* b2 = (const float*)d_in[5];
    const float* W3 = (const float*)d_in[6];
    const float* b3 = (const float*)d_in[7];
    const float* Wl = (const float*)d_in[8];
    const float* bl = (const float*)d_in[9];
    float* out = (float*)d_out;

    // workspace layout
    float* bufA  = (float*)d_ws;                       // N*128 (8 panels)
    float* bufB  = bufA + (size_t)N_NODES * 128;       // N*128 (8 panels)
    float* dinv  = bufB + (size_t)N_NODES * 128;       // N
    float* colw  = dinv + N_NODES;                     // E
    int*   col   = (int*)(colw + N_EDGES);             // E
    int*   cnt   = col + N_EDGES;                      // N   <- memset base
    int*   fill  = cnt + N_NODES;                      // N
    int*   total = fill + N_NODES;                     // 1
    int*   start = total + 1;                          // N

    hipMemsetAsync(cnt, 0, (size_t)(2 * N_NODES + 1) * sizeof(int), stream);
    count_edges <<<(N_EDGES + 255) / 256, 256, 0, stream>>>(dstArr, cnt);
    reserve_rows<<<(N_NODES + 255) / 256, 256, 0, stream>>>(cnt, start, total, dinv);
    csr_fill    <<<(N_EDGES + 255) / 256, 256, 0, stream>>>(srcArr, dstArr, start, fill, col, colw, dinv);

    const int GEMM_GRID = (N_NODES + 63) / 64;           // 782
    const int AGG_GRID  = ((N_NODES + 63) / 64) * 8;     // 6256: blockIdx%8 = panel/XCD

    gemm128_t<false><<<GEMM_GRID, 256, 0, stream>>>(x, W1, bufA);
    gcn_aggregate_pn<<<AGG_GRID, 256, 0, stream>>>(bufA, start, cnt, col, colw, dinv, b1, bufB);
    gemm128_t<true><<<GEMM_GRID, 256, 0, stream>>>(bufB, W2, bufA);
    gcn_aggregate_pn<<<AGG_GRID, 256, 0, stream>>>(bufA, start, cnt, col, colw, dinv, b2, bufB);
    gemm128_t<true><<<GEMM_GRID, 256, 0, stream>>>(bufB, W3, bufA);
    gcn_aggregate_pn<<<AGG_GRID, 256, 0, stream>>>(bufA, start, cnt, col, colw, dinv, b3, bufB);
    gemm_final_pn<<<N_NODES / 8, 256, 0, stream>>>(bufB, Wl, bl, out);
}